// Round 5
// baseline (31.402 us; speedup 1.0000x reference)
//
#include <hip/hip_runtime.h>
#include <math.h>

#define BINS 30
#define QDIM 32
#define DDIM 8192
#define NCOPY 8                  // histogram copies (collision dilution)
#define NBLK 2048                // exactly-resident: 8 blocks/CU x 256 CUs

// Single persistent-style kernel. Grid = 2048 blocks x 256 threads
// (32 waves/CU resident in one dispatch wave). Each block processes
// rows bq = blockIdx.x and blockIdx.x + 2048.
// Hot loop per row: 1 float4 simmat load + 1 int4 dtoks load (L2-resident,
// proven free in R3) + bin math + 4 unconditional DS atomics into an
// 8-copy interleaved histogram; invalid elements go to trash bin 30.
__global__ __launch_bounds__(256, 8) void drmm_hist_kernel(
    const float* __restrict__ simmat,
    const int*   __restrict__ dtoks,
    const int*   __restrict__ qtoks,
    float*       __restrict__ out)
{
    const int t = threadIdx.x;
    const int c = t & (NCOPY - 1);                 // this lane's histogram copy

    __shared__ int hist[(BINS + 1) * NCOPY];       // 31 bins x 8 copies = 248 words

    for (int bq = blockIdx.x; bq < NBLK * 2; bq += NBLK) {
        const int b = bq >> 5;                     // Q == 32

        // clear histogram
        if (t < (BINS + 1) * NCOPY) hist[t] = 0;
        __syncthreads();

        const bool qvalid = (qtoks[bq] != 0);
        const float4* __restrict__ srow =
            reinterpret_cast<const float4*>(simmat + (size_t)bq * DDIM);
        const int4* __restrict__ drow =
            reinterpret_cast<const int4*>(dtoks + (size_t)b * DDIM);

        // 8192 elements / (256 threads * 4 per thread) = 8 iterations
#pragma unroll
        for (int it = 0; it < 8; ++it) {
            const int v = it * 256 + t;            // float4 index within row
            const float4 s  = srow[v];
            const int4   dt = drow[v];

            // bin = trunc(((s + 1.000001f) / 2.0f) * 29.0f) -- XLA f32 op order
            int bin0 = (int)(((s.x + 1.000001f) / 2.0f) * 29.0f);
            int bin1 = (int)(((s.y + 1.000001f) / 2.0f) * 29.0f);
            int bin2 = (int)(((s.z + 1.000001f) / 2.0f) * 29.0f);
            int bin3 = (int)(((s.w + 1.000001f) / 2.0f) * 29.0f);
            // clamp for LDS safety (no-op for inputs in [-1,1])
            bin0 = min(max(bin0, 0), BINS - 1);
            bin1 = min(max(bin1, 0), BINS - 1);
            bin2 = min(max(bin2, 0), BINS - 1);
            bin3 = min(max(bin3, 0), BINS - 1);
            // invalid elements -> trash bin 30 (unconditional atomics, no exec churn)
            bin0 = (qvalid && dt.x != 0) ? bin0 : BINS;
            bin1 = (qvalid && dt.y != 0) ? bin1 : BINS;
            bin2 = (qvalid && dt.z != 0) ? bin2 : BINS;
            bin3 = (qvalid && dt.w != 0) ? bin3 : BINS;

            atomicAdd(&hist[bin0 * NCOPY + c], 1);
            atomicAdd(&hist[bin1 * NCOPY + c], 1);
            atomicAdd(&hist[bin2 * NCOPY + c], 1);
            atomicAdd(&hist[bin3 * NCOPY + c], 1);
        }
        __syncthreads();

        if (t < BINS) {
            const int* h = &hist[t * NCOPY];
            const int cnt = h[0] + h[1] + h[2] + h[3] + h[4] + h[5] + h[6] + h[7];
            out[(size_t)bq * BINS + t] = logf((float)cnt + 1e-5f);
        }
        __syncthreads();   // hist reads done before next row's clear
    }
}

extern "C" void kernel_launch(void* const* d_in, const int* in_sizes, int n_in,
                              void* d_out, int out_size, void* d_ws, size_t ws_size,
                              hipStream_t stream) {
    const float* simmat = (const float*)d_in[0];  // [B,Q,D] f32
    const int*   dtoks  = (const int*)d_in[1];    // [B,D]
    const int*   qtoks  = (const int*)d_in[2];    // [B,Q]
    float*       out    = (float*)d_out;          // [B,Q,BINS]

    drmm_hist_kernel<<<NBLK, 256, 0, stream>>>(simmat, dtoks, qtoks, out);
}